// Round 6
// baseline (224.397 us; speedup 1.0000x reference)
//
#include <hip/hip_runtime.h>
#include <hip/hip_fp16.h>
#include <math.h>

#define NEG_SLOPE 0.2f
#define SCAN_CHUNK 2048     // per-block elements in hierarchical scan (256 thr * 8)
#define BUCKET_SHIFT 8      // 256 nodes per bucket
#define BUCKET_MASK 255
#define EB_CHUNK 8192       // edges per partition block (256 thr * 32)
#define EL_CAP 4992         // LDS-cached e-values per bucket (Poisson(4096), 14 sigma)
#define FENC_NEGINF 0x007FFFFFu

__device__ __forceinline__ float lrelu(float e) {
    return e > 0.f ? e : NEG_SLOPE * e;
}
// monotone float<->uint encode for atomicMax on floats (any sign)
__device__ __forceinline__ unsigned fenc(float f) {
    unsigned u = __float_as_uint(f);
    return (u & 0x80000000u) ? ~u : (u | 0x80000000u);
}
__device__ __forceinline__ float fdec(unsigned u) {
    unsigned b = (u & 0x80000000u) ? (u & 0x7FFFFFFFu) : ~u;
    return __uint_as_float(b);
}

// ---------------- Layer-1 node prep: h1[N,32] (fp16), as1[N,2], ad1[N,2] ----
__global__ void k0_prep1(const float* __restrict__ x,
                         const float* __restrict__ W1,
                         const float* __restrict__ a_src1,
                         const float* __restrict__ a_dst1,
                         __half* __restrict__ h1,
                         float* __restrict__ as1,
                         float* __restrict__ ad1,
                         int N) {
    int t = blockIdx.x * blockDim.x + threadIdx.x;
    int n = t >> 5;
    int c = t & 31;
    if (n >= N) return;
    const float4 xv = reinterpret_cast<const float4*>(x)[n];
    float h = xv.x * W1[c] + xv.y * W1[32 + c] + xv.z * W1[64 + c] + xv.w * W1[96 + c];
    h1[n * 32 + c] = __float2half(h);
    float ts = h * a_src1[c];
    float td = h * a_dst1[c];
#pragma unroll
    for (int m = 8; m >= 1; m >>= 1) {
        ts += __shfl_xor(ts, m);
        td += __shfl_xor(td, m);
    }
    if ((c & 15) == 0) {
        int hh = c >> 4;
        as1[n * 2 + hh] = ts;
        ad1[n * 2 + hh] = td;
    }
}

// ---------------- CSR build: two-level counting sort (no global atomics) ----
__global__ void p1_hist(const int* __restrict__ dst, int* __restrict__ cmatT,
                        int E, int NB, int nblkE) {
    __shared__ int cnt[512];
    const int blk = blockIdx.x, tid = threadIdx.x;
    for (int b = tid; b < NB; b += 256) cnt[b] = 0;
    __syncthreads();
    int base = blk * EB_CHUNK;
    int end = min(base + EB_CHUNK, E);
    for (int e = base + tid; e < end; e += 256)
        atomicAdd(&cnt[dst[e] >> BUCKET_SHIFT], 1);
    __syncthreads();
    for (int b = tid; b < NB; b += 256)
        cmatT[(size_t)b * nblkE + blk] = cnt[b];
}

// --------- hierarchical exclusive scan (generic, over n ints) ---------------
__global__ void k2a_partials(const int* __restrict__ in, int* __restrict__ bsum, int n) {
    __shared__ int ws[4];
    const int tid = threadIdx.x;
    const int lane = tid & 63, wid = tid >> 6;
    int base = blockIdx.x * SCAN_CHUNK + tid * 8;
    int lsum = 0;
#pragma unroll
    for (int i = 0; i < 8; ++i) {
        int idx = base + i;
        lsum += (idx < n) ? in[idx] : 0;
    }
#pragma unroll
    for (int m = 32; m >= 1; m >>= 1) lsum += __shfl_xor(lsum, m);
    if (lane == 0) ws[wid] = lsum;
    __syncthreads();
    if (tid == 0) bsum[blockIdx.x] = ws[0] + ws[1] + ws[2] + ws[3];
}

__global__ void k2b_scanb(const int* __restrict__ bsum, int* __restrict__ bscan, int nb) {
    __shared__ int wsum[16];
    const int tid = threadIdx.x;
    const int lane = tid & 63, wid = tid >> 6;
    int carry = 0;
    for (int base = 0; base < nb; base += 1024) {
        int i = base + tid;
        int v = (i < nb) ? bsum[i] : 0;
        int xx = v;
#pragma unroll
        for (int off = 1; off < 64; off <<= 1) {
            int t = __shfl_up(xx, off);
            if (lane >= off) xx += t;
        }
        if (lane == 63) wsum[wid] = xx;
        __syncthreads();
        int woff = 0;
        for (int w = 0; w < wid; ++w) woff += wsum[w];
        if (i < nb) bscan[i] = carry + woff + xx - v;
        int tot = 0;
        for (int w = 0; w < 16; ++w) tot += wsum[w];
        carry += tot;
        __syncthreads();
    }
}

__global__ void k2c_scan(const int* __restrict__ in, const int* __restrict__ bscan,
                         int* __restrict__ out, int n) {
    __shared__ int ws[4];
    const int tid = threadIdx.x;
    const int lane = tid & 63, wid = tid >> 6;
    int base = blockIdx.x * SCAN_CHUNK + tid * 8;
    int v[8], pre[8];
    int lsum = 0;
#pragma unroll
    for (int i = 0; i < 8; ++i) {
        int idx = base + i;
        v[i] = (idx < n) ? in[idx] : 0;
        pre[i] = lsum;
        lsum += v[i];
    }
    int xs = lsum;
#pragma unroll
    for (int off = 1; off < 64; off <<= 1) {
        int t = __shfl_up(xs, off);
        if (lane >= off) xs += t;
    }
    if (lane == 63) ws[wid] = xs;
    __syncthreads();
    int woff = 0;
    for (int w = 0; w < wid; ++w) woff += ws[w];
    int off0 = bscan[blockIdx.x] + woff + xs - lsum;
#pragma unroll
    for (int i = 0; i < 8; ++i) {
        int idx = base + i;
        if (idx < n) out[idx] = off0 + pre[i];
    }
}

// P3: scatter edges into bucket-partitioned ebuf via LDS cursors
__global__ void p3_scatter(const int* __restrict__ src, const int* __restrict__ dst,
                           const int* __restrict__ cscan, unsigned int* __restrict__ ebuf,
                           int E, int NB, int nblkE) {
    __shared__ int cur[512];
    const int blk = blockIdx.x, tid = threadIdx.x;
    for (int b = tid; b < NB; b += 256)
        cur[b] = cscan[(size_t)b * nblkE + blk];
    __syncthreads();
    int base = blk * EB_CHUNK;
    int end = min(base + EB_CHUNK, E);
    for (int e = base + tid; e < end; e += 256) {
        int d = dst[e];
        int b = d >> BUCKET_SHIFT;
        int pos = atomicAdd(&cur[b], 1);
        ebuf[pos] = (unsigned int)src[e] | ((unsigned int)(d & BUCKET_MASK) << 24);
    }
}

// P4: per-bucket CSR finalize + edge-parallel attention weights
//   Pass A: hist(dl) + e = lrelu(as1[src]+ad1[dst]) -> LDS, per-(node,head) max
//   scan -> rp/cursors
//   Pass B: w = exp(e-m) -> wgtH (half2), per-(node,head) sum, scatter esrt
//   writes nst[n] = (m0, m1, s0, s1)
__global__ void p4_csr(const unsigned int* __restrict__ ebuf,
                       const int* __restrict__ cscan,
                       const float* __restrict__ as1,
                       const float* __restrict__ ad1,
                       int* __restrict__ rp, int* __restrict__ esrt,
                       __half2* __restrict__ wgtH, float4* __restrict__ nst,
                       int N, int E, int NB, int nblkE) {
    __shared__ float2 eL[EL_CAP];
    __shared__ unsigned maxL[512];
    __shared__ float ssumL[512];
    __shared__ int degl[256];
    __shared__ int curl[256];
    __shared__ float2 adL[256];
    __shared__ int wsum[4];
    const int b = blockIdx.x, tid = threadIdx.x;
    const int lane = tid & 63, wid = tid >> 6;
    const float2* as1v = reinterpret_cast<const float2*>(as1);
    const float2* ad1v = reinterpret_cast<const float2*>(ad1);
    int bstart = cscan[(size_t)b * nblkE];
    int bend = (b + 1 < NB) ? cscan[(size_t)(b + 1) * nblkE] : E;
    int node = (b << BUCKET_SHIFT) + tid;
    degl[tid] = 0;
    maxL[tid] = FENC_NEGINF;
    maxL[tid + 256] = FENC_NEGINF;
    ssumL[tid] = 0.f;
    ssumL[tid + 256] = 0.f;
    adL[tid] = (node < N) ? ad1v[node] : make_float2(0.f, 0.f);
    __syncthreads();
    // Pass A
    for (int i = bstart + tid; i < bend; i += 256) {
        unsigned ev = ebuf[i];
        int dl = ev >> 24;
        int srcn = ev & 0x00FFFFFF;
        atomicAdd(&degl[dl], 1);
        float2 av = as1v[srcn];                  // random 8B gather (L2/L3)
        float2 adv = adL[dl];
        float e0 = lrelu(av.x + adv.x);
        float e1 = lrelu(av.y + adv.y);
        int sl = i - bstart;
        if (sl < EL_CAP) eL[sl] = make_float2(e0, e1);
        atomicMax(&maxL[dl * 2], fenc(e0));
        atomicMax(&maxL[dl * 2 + 1], fenc(e1));
    }
    __syncthreads();
    // exclusive scan of degl -> per-node start offsets
    int v = degl[tid];
    int xs = v;
#pragma unroll
    for (int off = 1; off < 64; off <<= 1) {
        int t = __shfl_up(xs, off);
        if (lane >= off) xs += t;
    }
    if (lane == 63) wsum[wid] = xs;
    __syncthreads();
    int woff = 0;
    for (int w = 0; w < wid; ++w) woff += wsum[w];
    int excl = woff + xs - v;
    if (node < N) rp[node] = bstart + excl;
    curl[tid] = bstart + excl;
    if (b == 0 && tid == 0) rp[N] = E;
    __syncthreads();
    // Pass B
    for (int i = bstart + tid; i < bend; i += 256) {
        unsigned ev = ebuf[i];
        int dl = ev >> 24;
        int srcn = ev & 0x00FFFFFF;
        int sl = i - bstart;
        float2 e;
        if (sl < EL_CAP) {
            e = eL[sl];
        } else {                                  // overflow fallback (never hit)
            float2 av = as1v[srcn];
            float2 adv = adL[dl];
            e = make_float2(lrelu(av.x + adv.x), lrelu(av.y + adv.y));
        }
        float m0 = fdec(maxL[dl * 2]);
        float m1 = fdec(maxL[dl * 2 + 1]);
        float w0 = __expf(e.x - m0);              // <= 1
        float w1 = __expf(e.y - m1);
        atomicAdd(&ssumL[dl * 2], w0);
        atomicAdd(&ssumL[dl * 2 + 1], w1);
        int pos = atomicAdd(&curl[dl], 1);
        esrt[pos] = srcn;
        wgtH[pos] = __floats2half2_rn(w0, w1);
    }
    __syncthreads();
    if (node < N)
        nst[node] = make_float4(fdec(maxL[tid * 2]), fdec(maxL[tid * 2 + 1]),
                                ssumL[tid * 2], ssumL[tid * 2 + 1]);
}

// ---------------- Layer-1 aggregate + fused ELU + layer-2 prep --------------
// 32 threads per node; weights precomputed; lane c owns channel c.
__global__ void k4_layer1(const int* __restrict__ rp, const int* __restrict__ esrt,
                          const __half2* __restrict__ wgtH,
                          const float4* __restrict__ nst,
                          const __half* __restrict__ h1, const float* __restrict__ as1,
                          const float* __restrict__ ad1, const float* __restrict__ b1,
                          const float* __restrict__ W2, const float* __restrict__ a_src2,
                          const float* __restrict__ a_dst2,
                          float4* __restrict__ h2p, float* __restrict__ ad2,
                          int N) {
    int t = blockIdx.x * blockDim.x + threadIdx.x;
    int n = t >> 5;
    int c = t & 31;
    if (n >= N) return;
    int hh = c >> 4;
    const float2* as1v = reinterpret_cast<const float2*>(as1);
    const float2* ad1v = reinterpret_cast<const float2*>(ad1);
    float2 adv = ad1v[n];
    float2 asv = as1v[n];
    float es = lrelu((hh ? asv.y : asv.x) + (hh ? adv.y : adv.x));
    float h_self = __half2float(h1[(size_t)n * 32 + c]);
    float4 ns = nst[n];
    int p0 = rp[n], p1 = rp[n + 1];
    float acc, stot;
    if (p0 == p1) {                               // isolated node: alpha_self = 1
        acc = h_self;
        stot = 1.f;
    } else {
        float m = hh ? ns.y : ns.x;
        float se = hh ? ns.w : ns.z;
        float w_self = __expf(es - m);            // bounded (same distribution)
        stot = se + w_self;
        float a0 = w_self * h_self, a1 = 0.f, a2 = 0.f, a3 = 0.f;
        int p = p0;
        for (; p + 3 < p1; p += 4) {              // 4 independent gather chains
            int sa = esrt[p];
            int sb = esrt[p + 1];
            int sc_ = esrt[p + 2];
            int sd = esrt[p + 3];
            __half2 wa = wgtH[p];
            __half2 wb = wgtH[p + 1];
            __half2 wc = wgtH[p + 2];
            __half2 wd = wgtH[p + 3];
            float ha = __half2float(h1[(size_t)sa * 32 + c]);
            float hb = __half2float(h1[(size_t)sb * 32 + c]);
            float hc = __half2float(h1[(size_t)sc_ * 32 + c]);
            float hd = __half2float(h1[(size_t)sd * 32 + c]);
            a0 += (hh ? __high2float(wa) : __low2float(wa)) * ha;
            a1 += (hh ? __high2float(wb) : __low2float(wb)) * hb;
            a2 += (hh ? __high2float(wc) : __low2float(wc)) * hc;
            a3 += (hh ? __high2float(wd) : __low2float(wd)) * hd;
        }
        for (; p < p1; ++p) {
            int sa = esrt[p];
            __half2 wa = wgtH[p];
            float ha = __half2float(h1[(size_t)sa * 32 + c]);
            a0 += (hh ? __high2float(wa) : __low2float(wa)) * ha;
        }
        acc = (a0 + a1) + (a2 + a3);
    }
    float o = acc / stot + b1[c];
    o = o > 0.f ? o : expm1f(o);                  // ELU
    // fused layer-2 prep: h2 = o @ W2 (reduce over all 32 channels)
    float t0 = o * W2[c * 2 + 0];
    float t1 = o * W2[c * 2 + 1];
#pragma unroll
    for (int msk = 16; msk >= 1; msk >>= 1) {
        t0 += __shfl_xor(t0, msk);
        t1 += __shfl_xor(t1, msk);
    }
    if (c == 0) {
        float as2v = t0 * a_src2[0] + t1 * a_src2[1];
        float ad2v = t0 * a_dst2[0] + t1 * a_dst2[1];
        h2p[n] = make_float4(t0, t1, as2v, 0.f);
        ad2[n] = ad2v;
    }
}

// ---------------- Layer-2 aggregate → output --------------------------------
// 4 lanes per node; each lane strides edges by 4; shfl combine.
__global__ void k5_layer2(const int* __restrict__ rp, const int* __restrict__ esrt,
                          const float4* __restrict__ h2p, const float* __restrict__ ad2,
                          const float* __restrict__ b2,
                          float* __restrict__ out, int N) {
    int t = blockIdx.x * blockDim.x + threadIdx.x;
    int n = t >> 2;
    int sub = t & 3;
    if (n >= N) return;
    float ad = ad2[n];
    float s = 0.f, xx = 0.f, yy = 0.f;
    if (sub == 0) {                               // self-loop
        float4 hv = h2p[n];
        float w = __expf(fminf(lrelu(hv.z + ad), 80.f));
        s = w; xx = w * hv.x; yy = w * hv.y;
    }
    int p0 = rp[n], p1 = rp[n + 1];
    for (int p = p0 + sub; p < p1; p += 4) {
        int sn = esrt[p];
        float4 hv = h2p[sn];                      // single 16B random gather
        float w = __expf(fminf(lrelu(hv.z + ad), 80.f));
        s += w; xx += w * hv.x; yy += w * hv.y;
    }
#pragma unroll
    for (int msk = 1; msk <= 2; msk <<= 1) {
        s  += __shfl_xor(s, msk);
        xx += __shfl_xor(xx, msk);
        yy += __shfl_xor(yy, msk);
    }
    if (sub == 0) {
        float2 o;
        o.x = xx / s + b2[0];
        o.y = yy / s + b2[1];
        reinterpret_cast<float2*>(out)[n] = o;
    }
}

extern "C" void kernel_launch(void* const* d_in, const int* in_sizes, int n_in,
                              void* d_out, int out_size, void* d_ws, size_t ws_size,
                              hipStream_t stream) {
    const float* x      = (const float*)d_in[0];
    const int*   ei     = (const int*)d_in[1];
    const float* W1     = (const float*)d_in[2];
    const float* a_src1 = (const float*)d_in[3];
    const float* a_dst1 = (const float*)d_in[4];
    const float* b1     = (const float*)d_in[5];
    const float* W2     = (const float*)d_in[6];
    const float* a_src2 = (const float*)d_in[7];
    const float* a_dst2 = (const float*)d_in[8];
    const float* b2     = (const float*)d_in[9];
    float* out = (float*)d_out;

    const int N = in_sizes[0] / 4;
    const int E = in_sizes[1] / 2;
    const int* srcp = ei;
    const int* dstp = ei + E;

    const int NB    = (N + BUCKET_MASK) >> BUCKET_SHIFT;
    const int nblkE = (E + EB_CHUNK - 1) / EB_CHUNK;
    const int M     = NB * nblkE;
    const int nb2   = (M + SCAN_CHUNK - 1) / SCAN_CHUNK;

    // workspace layout (keep float4 arrays 16B-aligned)
    char* w = (char*)d_ws;
    __half* h1   = (__half*)w;  w += (size_t)N * 32 * sizeof(__half);
    float*  as1  = (float*)w;   w += (size_t)N * 2 * sizeof(float);
    float*  ad1  = (float*)w;   w += (size_t)N * 2 * sizeof(float);
    float4* h2p  = (float4*)w;  w += (size_t)N * sizeof(float4);
    float*  ad2  = (float*)w;   w += (size_t)N * sizeof(float);
    float4* nst  = (float4*)w;  w += (size_t)N * sizeof(float4);
    int* rp     = (int*)w;      w += (size_t)(N + 4) * sizeof(int);
    int* cmatT  = (int*)w;      w += (size_t)M * sizeof(int);
    int* cscan  = (int*)w;      w += (size_t)M * sizeof(int);
    int* bsum   = (int*)w;      w += (size_t)(nb2 + 4) * sizeof(int);
    int* bscan  = (int*)w;      w += (size_t)(nb2 + 4) * sizeof(int);
    unsigned int* ebuf = (unsigned int*)w;  w += (size_t)E * sizeof(unsigned int);
    int* esrt   = (int*)w;      w += (size_t)E * sizeof(int);
    __half2* wgtH = (__half2*)w; w += (size_t)E * sizeof(__half2);

    const int BT = 256;
    k0_prep1<<<((size_t)N * 32 + BT - 1) / BT, BT, 0, stream>>>(
        x, W1, a_src1, a_dst1, h1, as1, ad1, N);
    p1_hist<<<nblkE, 256, 0, stream>>>(dstp, cmatT, E, NB, nblkE);
    k2a_partials<<<nb2, 256, 0, stream>>>(cmatT, bsum, M);
    k2b_scanb<<<1, 1024, 0, stream>>>(bsum, bscan, nb2);
    k2c_scan<<<nb2, 256, 0, stream>>>(cmatT, bscan, cscan, M);
    p3_scatter<<<nblkE, 256, 0, stream>>>(srcp, dstp, cscan, ebuf, E, NB, nblkE);
    p4_csr<<<NB, 256, 0, stream>>>(ebuf, cscan, as1, ad1, rp, esrt, wgtH, nst,
                                   N, E, NB, nblkE);
    k4_layer1<<<((size_t)N * 32 + BT - 1) / BT, BT, 0, stream>>>(
        rp, esrt, wgtH, nst, h1, as1, ad1, b1, W2, a_src2, a_dst2, h2p, ad2, N);
    k5_layer2<<<((size_t)N * 4 + BT - 1) / BT, BT, 0, stream>>>(
        rp, esrt, h2p, ad2, b2, out, N);
}

// Round 7
// 179.179 us; speedup vs baseline: 1.2524x; 1.2524x over previous
//
#include <hip/hip_runtime.h>
#include <math.h>

#define NEG_SLOPE 0.2f
#define SCAN_CHUNK 2048     // per-block elements in hierarchical scan (256 thr * 8)
#define ECLAMP 80.0f        // exp() inf-safety clamp (never hit statistically)
#define BUCKET_SHIFT 8      // 256 nodes per bucket
#define BUCKET_MASK 255
#define EB_CHUNK 8192       // edges per partition block (256 thr * 32)

__device__ __forceinline__ float lrelu(float e) {
    return e > 0.f ? e : NEG_SLOPE * e;
}

// ---------------- Layer-1 node prep: as1[N,2], ad1[N,2] (h1 never stored) ---
// 32 threads per node; lane c owns channel c (head = c>>4).
__global__ void k0_prep1(const float* __restrict__ x,
                         const float* __restrict__ W1,
                         const float* __restrict__ a_src1,
                         const float* __restrict__ a_dst1,
                         float* __restrict__ as1,
                         float* __restrict__ ad1,
                         int N) {
    int t = blockIdx.x * blockDim.x + threadIdx.x;
    int n = t >> 5;
    int c = t & 31;
    if (n >= N) return;
    const float4 xv = reinterpret_cast<const float4*>(x)[n];
    float h = xv.x * W1[c] + xv.y * W1[32 + c] + xv.z * W1[64 + c] + xv.w * W1[96 + c];
    float ts = h * a_src1[c];
    float td = h * a_dst1[c];
#pragma unroll
    for (int m = 8; m >= 1; m >>= 1) {        // reduce over 16 channels of this head
        ts += __shfl_xor(ts, m);
        td += __shfl_xor(td, m);
    }
    if ((c & 15) == 0) {
        int hh = c >> 4;
        as1[n * 2 + hh] = ts;
        ad1[n * 2 + hh] = td;
    }
}

// ---------------- CSR build: two-level counting sort (no global atomics) ----
__global__ void p1_hist(const int* __restrict__ dst, int* __restrict__ cmatT,
                        int E, int NB, int nblkE) {
    __shared__ int cnt[512];
    const int blk = blockIdx.x, tid = threadIdx.x;
    for (int b = tid; b < NB; b += 256) cnt[b] = 0;
    __syncthreads();
    int base = blk * EB_CHUNK;
    int end = min(base + EB_CHUNK, E);
    for (int e = base + tid; e < end; e += 256)
        atomicAdd(&cnt[dst[e] >> BUCKET_SHIFT], 1);
    __syncthreads();
    for (int b = tid; b < NB; b += 256)
        cmatT[(size_t)b * nblkE + blk] = cnt[b];
}

// --------- hierarchical exclusive scan (generic, over n ints) ---------------
__global__ void k2a_partials(const int* __restrict__ in, int* __restrict__ bsum, int n) {
    __shared__ int ws[4];
    const int tid = threadIdx.x;
    const int lane = tid & 63, wid = tid >> 6;
    int base = blockIdx.x * SCAN_CHUNK + tid * 8;
    int lsum = 0;
#pragma unroll
    for (int i = 0; i < 8; ++i) {
        int idx = base + i;
        lsum += (idx < n) ? in[idx] : 0;
    }
#pragma unroll
    for (int m = 32; m >= 1; m >>= 1) lsum += __shfl_xor(lsum, m);
    if (lane == 0) ws[wid] = lsum;
    __syncthreads();
    if (tid == 0) bsum[blockIdx.x] = ws[0] + ws[1] + ws[2] + ws[3];
}

__global__ void k2b_scanb(const int* __restrict__ bsum, int* __restrict__ bscan, int nb) {
    __shared__ int wsum[16];
    const int tid = threadIdx.x;
    const int lane = tid & 63, wid = tid >> 6;
    int carry = 0;
    for (int base = 0; base < nb; base += 1024) {
        int i = base + tid;
        int v = (i < nb) ? bsum[i] : 0;
        int xx = v;
#pragma unroll
        for (int off = 1; off < 64; off <<= 1) {
            int t = __shfl_up(xx, off);
            if (lane >= off) xx += t;
        }
        if (lane == 63) wsum[wid] = xx;
        __syncthreads();
        int woff = 0;
        for (int w = 0; w < wid; ++w) woff += wsum[w];
        if (i < nb) bscan[i] = carry + woff + xx - v;
        int tot = 0;
        for (int w = 0; w < 16; ++w) tot += wsum[w];
        carry += tot;
        __syncthreads();
    }
}

__global__ void k2c_scan(const int* __restrict__ in, const int* __restrict__ bscan,
                         int* __restrict__ out, int n) {
    __shared__ int ws[4];
    const int tid = threadIdx.x;
    const int lane = tid & 63, wid = tid >> 6;
    int base = blockIdx.x * SCAN_CHUNK + tid * 8;
    int v[8], pre[8];
    int lsum = 0;
#pragma unroll
    for (int i = 0; i < 8; ++i) {
        int idx = base + i;
        v[i] = (idx < n) ? in[idx] : 0;
        pre[i] = lsum;
        lsum += v[i];
    }
    int xs = lsum;
#pragma unroll
    for (int off = 1; off < 64; off <<= 1) {
        int t = __shfl_up(xs, off);
        if (lane >= off) xs += t;
    }
    if (lane == 63) ws[wid] = xs;
    __syncthreads();
    int woff = 0;
    for (int w = 0; w < wid; ++w) woff += ws[w];
    int off0 = bscan[blockIdx.x] + woff + xs - lsum;
#pragma unroll
    for (int i = 0; i < 8; ++i) {
        int idx = base + i;
        if (idx < n) out[idx] = off0 + pre[i];
    }
}

// P3: scatter edges into bucket-partitioned ebuf via LDS cursors
__global__ void p3_scatter(const int* __restrict__ src, const int* __restrict__ dst,
                           const int* __restrict__ cscan, unsigned int* __restrict__ ebuf,
                           int E, int NB, int nblkE) {
    __shared__ int cur[512];
    const int blk = blockIdx.x, tid = threadIdx.x;
    for (int b = tid; b < NB; b += 256)
        cur[b] = cscan[(size_t)b * nblkE + blk];
    __syncthreads();
    int base = blk * EB_CHUNK;
    int end = min(base + EB_CHUNK, E);
    for (int e = base + tid; e < end; e += 256) {
        int d = dst[e];
        int b = d >> BUCKET_SHIFT;
        int pos = atomicAdd(&cur[b], 1);
        ebuf[pos] = (unsigned int)src[e] | ((unsigned int)(d & BUCKET_MASK) << 24);
    }
}

// P4: per-bucket CSR finalize: local hist -> local scan -> rp + esrt
__global__ void p4_csr(const unsigned int* __restrict__ ebuf,
                       const int* __restrict__ cscan,
                       int* __restrict__ rp, int* __restrict__ esrt,
                       int N, int E, int NB, int nblkE) {
    __shared__ int degl[256];
    __shared__ int curl[256];
    __shared__ int wsum[4];
    const int b = blockIdx.x, tid = threadIdx.x;
    const int lane = tid & 63, wid = tid >> 6;
    int bstart = cscan[(size_t)b * nblkE];
    int bend = (b + 1 < NB) ? cscan[(size_t)(b + 1) * nblkE] : E;
    degl[tid] = 0;
    __syncthreads();
    for (int i = bstart + tid; i < bend; i += 256)
        atomicAdd(&degl[ebuf[i] >> 24], 1);
    __syncthreads();
    int v = degl[tid];
    int xs = v;
#pragma unroll
    for (int off = 1; off < 64; off <<= 1) {
        int t = __shfl_up(xs, off);
        if (lane >= off) xs += t;
    }
    if (lane == 63) wsum[wid] = xs;
    __syncthreads();
    int woff = 0;
    for (int w = 0; w < wid; ++w) woff += wsum[w];
    int excl = woff + xs - v;
    int node = (b << BUCKET_SHIFT) + tid;
    if (node < N) rp[node] = bstart + excl;
    curl[tid] = bstart + excl;
    if (b == 0 && tid == 0) rp[N] = E;
    __syncthreads();
    for (int i = bstart + tid; i < bend; i += 256) {
        unsigned int ev = ebuf[i];
        int dl = ev >> 24;
        int pos = atomicAdd(&curl[dl], 1);
        esrt[pos] = (int)(ev & 0x00FFFFFFu);
    }
}

// ---------------- Layer-1 aggregate in x-space + fused epilogue --------------
// 8 lanes per node: lane l -> (head h = l>>2, dim d = l&3).
// Aggregates 4-dim x features (h1 = x@W1 is linear), recomputes attention
// weights inline from the L2-hot as1 table. Fused: /s, @W1, +b1, ELU, @W2,
// as2/ad2 -> h2p.
__global__ void k4_layer1(const int* __restrict__ rp, const int* __restrict__ esrt,
                          const float* __restrict__ x, const float* __restrict__ as1,
                          const float* __restrict__ ad1, const float* __restrict__ b1,
                          const float* __restrict__ W1,
                          const float* __restrict__ W2, const float* __restrict__ a_src2,
                          const float* __restrict__ a_dst2,
                          float4* __restrict__ h2p, float* __restrict__ ad2,
                          int N) {
    int t = blockIdx.x * blockDim.x + threadIdx.x;
    int n = t >> 3;
    int l = t & 7;
    if (n >= N) return;
    int h = l >> 2;         // head
    int d = l & 3;          // x-dim
    float ad = ad1[n * 2 + h];
    // self-loop
    float es = lrelu(as1[n * 2 + h] + ad);
    float ws = __expf(fminf(es, ECLAMP));
    float g0 = ws * x[(size_t)n * 4 + d], g1 = 0.f, g2 = 0.f, g3 = 0.f;
    float s0 = ws, s1 = 0.f, s2 = 0.f, s3 = 0.f;

    int p0 = rp[n], p1 = rp[n + 1];
    int p = p0;
    for (; p + 3 < p1; p += 4) {              // 4 independent gather chains
        int sa = esrt[p];
        int sb = esrt[p + 1];
        int sc_ = esrt[p + 2];
        int sd = esrt[p + 3];
        float ea = lrelu(as1[(size_t)sa * 2 + h] + ad);
        float eb = lrelu(as1[(size_t)sb * 2 + h] + ad);
        float ec = lrelu(as1[(size_t)sc_ * 2 + h] + ad);
        float ed = lrelu(as1[(size_t)sd * 2 + h] + ad);
        float xa = x[(size_t)sa * 4 + d];
        float xb = x[(size_t)sb * 4 + d];
        float xc = x[(size_t)sc_ * 4 + d];
        float xd = x[(size_t)sd * 4 + d];
        float wa = __expf(fminf(ea, ECLAMP));
        float wb = __expf(fminf(eb, ECLAMP));
        float wc = __expf(fminf(ec, ECLAMP));
        float wd = __expf(fminf(ed, ECLAMP));
        s0 += wa;  g0 += wa * xa;
        s1 += wb;  g1 += wb * xb;
        s2 += wc;  g2 += wc * xc;
        s3 += wd;  g3 += wd * xd;
    }
    for (; p < p1; ++p) {
        int sa = esrt[p];
        float ea = lrelu(as1[(size_t)sa * 2 + h] + ad);
        float xa = x[(size_t)sa * 4 + d];
        float wa = __expf(fminf(ea, ECLAMP));
        s0 += wa;  g0 += wa * xa;
    }
    float s = (s0 + s1) + (s2 + s3);
    float agg = ((g0 + g1) + (g2 + g3)) / s;   // aggregated x, this (h,d)

    // collect all 8 (h,d) agg values within the 8-lane segment
    float a2[2][4];
#pragma unroll
    for (int k = 0; k < 8; ++k)
        a2[k >> 2][k & 3] = __shfl(agg, k, 8);

    // lane computes channels c = l*4 .. l*4+3
    float t0 = 0.f, t1 = 0.f;
#pragma unroll
    for (int j = 0; j < 4; ++j) {
        int c = l * 4 + j;
        int hc = c >> 4;
        float o = b1[c]
                + a2[hc][0] * W1[c]
                + a2[hc][1] * W1[32 + c]
                + a2[hc][2] * W1[64 + c]
                + a2[hc][3] * W1[96 + c];
        o = o > 0.f ? o : expm1f(o);           // ELU
        t0 += o * W2[c * 2 + 0];
        t1 += o * W2[c * 2 + 1];
    }
#pragma unroll
    for (int msk = 1; msk <= 4; msk <<= 1) {   // reduce over 8-lane segment
        t0 += __shfl_xor(t0, msk);
        t1 += __shfl_xor(t1, msk);
    }
    if (l == 0) {
        float as2v = t0 * a_src2[0] + t1 * a_src2[1];
        float ad2v = t0 * a_dst2[0] + t1 * a_dst2[1];
        h2p[n] = make_float4(t0, t1, as2v, 0.f);
        ad2[n] = ad2v;
    }
}

// ---------------- Layer-2 aggregate → output --------------------------------
// 4 lanes per node; each lane strides edges by 4; shfl combine.
__global__ void k5_layer2(const int* __restrict__ rp, const int* __restrict__ esrt,
                          const float4* __restrict__ h2p, const float* __restrict__ ad2,
                          const float* __restrict__ b2,
                          float* __restrict__ out, int N) {
    int t = blockIdx.x * blockDim.x + threadIdx.x;
    int n = t >> 2;
    int sub = t & 3;
    if (n >= N) return;
    float ad = ad2[n];
    float s = 0.f, xx = 0.f, yy = 0.f;
    if (sub == 0) {                            // self-loop
        float4 hv = h2p[n];
        float w = __expf(fminf(lrelu(hv.z + ad), ECLAMP));
        s = w; xx = w * hv.x; yy = w * hv.y;
    }
    int p0 = rp[n], p1 = rp[n + 1];
    for (int p = p0 + sub; p < p1; p += 4) {
        int sn = esrt[p];
        float4 hv = h2p[sn];                   // single 16B random gather
        float w = __expf(fminf(lrelu(hv.z + ad), ECLAMP));
        s += w; xx += w * hv.x; yy += w * hv.y;
    }
#pragma unroll
    for (int msk = 1; msk <= 2; msk <<= 1) {
        s  += __shfl_xor(s, msk);
        xx += __shfl_xor(xx, msk);
        yy += __shfl_xor(yy, msk);
    }
    if (sub == 0) {
        float2 o;
        o.x = xx / s + b2[0];
        o.y = yy / s + b2[1];
        reinterpret_cast<float2*>(out)[n] = o;
    }
}

extern "C" void kernel_launch(void* const* d_in, const int* in_sizes, int n_in,
                              void* d_out, int out_size, void* d_ws, size_t ws_size,
                              hipStream_t stream) {
    const float* x      = (const float*)d_in[0];
    const int*   ei     = (const int*)d_in[1];
    const float* W1     = (const float*)d_in[2];
    const float* a_src1 = (const float*)d_in[3];
    const float* a_dst1 = (const float*)d_in[4];
    const float* b1     = (const float*)d_in[5];
    const float* W2     = (const float*)d_in[6];
    const float* a_src2 = (const float*)d_in[7];
    const float* a_dst2 = (const float*)d_in[8];
    const float* b2     = (const float*)d_in[9];
    float* out = (float*)d_out;

    const int N = in_sizes[0] / 4;
    const int E = in_sizes[1] / 2;
    const int* srcp = ei;
    const int* dstp = ei + E;

    const int NB    = (N + BUCKET_MASK) >> BUCKET_SHIFT;
    const int nblkE = (E + EB_CHUNK - 1) / EB_CHUNK;
    const int M     = NB * nblkE;
    const int nb2   = (M + SCAN_CHUNK - 1) / SCAN_CHUNK;

    // workspace layout (h2p first for 16B alignment)
    char* w = (char*)d_ws;
    float4* h2p  = (float4*)w;  w += (size_t)N * sizeof(float4);
    float*  as1  = (float*)w;   w += (size_t)N * 2 * sizeof(float);
    float*  ad1  = (float*)w;   w += (size_t)N * 2 * sizeof(float);
    float*  ad2  = (float*)w;   w += (size_t)N * sizeof(float);
    int* rp     = (int*)w;      w += (size_t)(N + 4) * sizeof(int);
    int* cmatT  = (int*)w;      w += (size_t)M * sizeof(int);
    int* cscan  = (int*)w;      w += (size_t)M * sizeof(int);
    int* bsum   = (int*)w;      w += (size_t)(nb2 + 4) * sizeof(int);
    int* bscan  = (int*)w;      w += (size_t)(nb2 + 4) * sizeof(int);
    unsigned int* ebuf = (unsigned int*)w;  w += (size_t)E * sizeof(unsigned int);
    int* esrt   = (int*)w;      w += (size_t)E * sizeof(int);

    const int BT = 256;
    k0_prep1<<<((size_t)N * 32 + BT - 1) / BT, BT, 0, stream>>>(
        x, W1, a_src1, a_dst1, as1, ad1, N);
    p1_hist<<<nblkE, 256, 0, stream>>>(dstp, cmatT, E, NB, nblkE);
    k2a_partials<<<nb2, 256, 0, stream>>>(cmatT, bsum, M);
    k2b_scanb<<<1, 1024, 0, stream>>>(bsum, bscan, nb2);
    k2c_scan<<<nb2, 256, 0, stream>>>(cmatT, bscan, cscan, M);
    p3_scatter<<<nblkE, 256, 0, stream>>>(srcp, dstp, cscan, ebuf, E, NB, nblkE);
    p4_csr<<<NB, 256, 0, stream>>>(ebuf, cscan, rp, esrt, N, E, NB, nblkE);
    k4_layer1<<<((size_t)N * 8 + BT - 1) / BT, BT, 0, stream>>>(
        rp, esrt, x, as1, ad1, b1, W1, W2, a_src2, a_dst2, h2p, ad2, N);
    k5_layer2<<<((size_t)N * 4 + BT - 1) / BT, BT, 0, stream>>>(
        rp, esrt, h2p, ad2, b2, out, N);
}